// Round 6
// baseline (751.050 us; speedup 1.0000x reference)
//
#include <hip/hip_runtime.h>

#define NN 50000
#define NF 256
#define NH 256
#define NC 40
#define NE 800000

typedef short bf16x8 __attribute__((ext_vector_type(8)));
typedef float f32x4 __attribute__((ext_vector_type(4)));

__device__ __forceinline__ unsigned short bf16_rn(float f) {
  union { float f; unsigned u; } a; a.f = f;
  unsigned r = ((a.u >> 16) & 1u) + 0x7FFFu;
  return (unsigned short)((a.u + r) >> 16);
}
__device__ __forceinline__ float bf16f(unsigned short h) {
  union { unsigned u; float f; } a; a.u = ((unsigned)h) << 16;
  return a.f;
}
__device__ __forceinline__ float f16f(unsigned short u) {
  union { unsigned short u; _Float16 h; } a; a.u = u;
  return (float)a.h;
}
__device__ __forceinline__ unsigned short f16u(float f) {
  union { unsigned short u; _Float16 h; } a; a.h = (_Float16)f;
  return a.u;
}

__device__ __forceinline__ void gl16(const void* g, void* l) {
  __builtin_amdgcn_global_load_lds(
      (const __attribute__((address_space(1))) unsigned int*)g,
      (__attribute__((address_space(3))) unsigned int*)l, 16, 0, 0);
}

// ---------------- preprocessing ----------------

__global__ void count_kernel(const int* __restrict__ dst, int* __restrict__ cnt) {
  int e = blockIdx.x * blockDim.x + threadIdx.x;
  if (e < NE) atomicAdd(&cnt[dst[e]], 1);
}

__global__ void dis_kernel(const int* __restrict__ cnt, float* __restrict__ dis) {
  int i = blockIdx.x * blockDim.x + threadIdx.x;
  if (i < NN) dis[i] = rsqrtf((float)(cnt[i] + 1));
}

__global__ __launch_bounds__(1024) void scan1_kernel(const int* __restrict__ cnt,
                                                     int* __restrict__ row_ptr,
                                                     int* __restrict__ bsum) {
  __shared__ int s[1024];
  int i = blockIdx.x * 1024 + threadIdx.x;
  int v = (i < NN) ? cnt[i] : 0;
  s[threadIdx.x] = v;
  __syncthreads();
  for (int ofs = 1; ofs < 1024; ofs <<= 1) {
    int t = (threadIdx.x >= ofs) ? s[threadIdx.x - ofs] : 0;
    __syncthreads();
    s[threadIdx.x] += t;
    __syncthreads();
  }
  if (i < NN) row_ptr[i] = s[threadIdx.x] - v;
  if (threadIdx.x == 1023) bsum[blockIdx.x] = s[1023];
}

__global__ void scan2_kernel(int* __restrict__ bsum) {
  int lane = threadIdx.x;
  const int nb = (NN + 1023) / 1024;
  int v = (lane < nb) ? bsum[lane] : 0;
  for (int ofs = 1; ofs < 64; ofs <<= 1) {
    int t = __shfl_up(v, ofs, 64);
    if (lane >= ofs) v += t;
  }
  if (lane < nb) bsum[lane] = v;
}

__global__ __launch_bounds__(1024) void scan3_kernel(int* __restrict__ row_ptr,
                                                     const int* __restrict__ bsum) {
  int i = blockIdx.x * 1024 + threadIdx.x;
  int add = (blockIdx.x > 0) ? bsum[blockIdx.x - 1] : 0;
  if (i < NN) row_ptr[i] += add;
  if (i == 0) row_ptr[NN] = NE;
}

__global__ void scatter_kernel(const int* __restrict__ src, const int* __restrict__ dst,
                               const int* __restrict__ row_ptr, int* __restrict__ cur,
                               int2* __restrict__ ew, const float* __restrict__ dis) {
  int e = blockIdx.x * blockDim.x + threadIdx.x;
  if (e < NE) {
    int d = dst[e], s = src[e];
    int pos = row_ptr[d] + atomicAdd(&cur[d], 1);
    int2 v; v.x = s; v.y = __float_as_int(dis[s] * dis[d]);
    ew[pos] = v;
  }
}

// ---------------- conversions ----------------

__global__ __launch_bounds__(256) void split_kernel(const float* __restrict__ x,
                                                    unsigned short* __restrict__ hi,
                                                    unsigned short* __restrict__ lo) {
  int i = blockIdx.x * blockDim.x + threadIdx.x;
  if (i >= NN * NF / 4) return;
  float4 v = ((const float4*)x)[i];
  ushort4 h, l;
  h.x = bf16_rn(v.x); l.x = bf16_rn(v.x - bf16f(h.x));
  h.y = bf16_rn(v.y); l.y = bf16_rn(v.y - bf16f(h.y));
  h.z = bf16_rn(v.z); l.z = bf16_rn(v.z - bf16f(h.z));
  h.w = bf16_rn(v.w); l.w = bf16_rn(v.w - bf16f(h.w));
  ((ushort4*)hi)[i] = h;
  ((ushort4*)lo)[i] = l;
}

__global__ void wsplit_kernel(const float* __restrict__ W,
                              unsigned short* __restrict__ Whi,
                              unsigned short* __restrict__ Wlo, int N, int NT) {
  int idx = blockIdx.x * blockDim.x + threadIdx.x;
  if (idx >= NT * 256) return;
  int n = idx >> 8, k = idx & 255;
  float v = (n < N) ? W[k * N + n] : 0.0f;
  unsigned short h = bf16_rn(v);
  Whi[idx] = h;
  Wlo[idx] = bf16_rn(v - bf16f(h));
}

// ---------------- split-bf16 MFMA GEMM: C = A[M][256] * Bt[*][256]^T ----------------
// F16OUT: write fp16 chunked layout [col/32][NN][32]; else f32 row-major [M][NSTORE].

template <int NSTORE, bool F16OUT>
__global__ __launch_bounds__(256, 2) void gemm_mfma(
    const unsigned short* __restrict__ Ahi, const unsigned short* __restrict__ Alo,
    const unsigned short* __restrict__ Bthi, const unsigned short* __restrict__ Btlo,
    void* __restrict__ Cout, int M) {
  __shared__ unsigned short lds[4][128 * 64];

  int tid = threadIdx.x;
  int rowBase = blockIdx.x * 128;
  int colBase = blockIdx.y * 128;
  int w = tid >> 6, lane = tid & 63;
  int wr = w >> 1, wc = w & 1;
  int l15 = lane & 15, l4 = lane >> 4;

  f32x4 acc[4][4] = {};

  for (int kt = 0; kt < 4; ++kt) {
#pragma unroll
    for (int c = 0; c < 4; ++c) {
      int gi = c * 256 + tid;
      int row = gi >> 3, gp = gi & 7;
      int gsrc = gp ^ (row & 7);
      int ar = rowBase + row; ar = ar < M ? ar : M - 1;
      int koff = kt * 64 + gsrc * 8;
      gl16(Ahi + (size_t)ar * 256 + koff, &lds[0][gi * 8]);
      gl16(Alo + (size_t)ar * 256 + koff, &lds[1][gi * 8]);
      int br = colBase + row;
      gl16(Bthi + (size_t)br * 256 + koff, &lds[2][gi * 8]);
      gl16(Btlo + (size_t)br * 256 + koff, &lds[3][gi * 8]);
    }
    __syncthreads();

#pragma unroll
    for (int ks = 0; ks < 2; ++ks) {
      bf16x8 ah[4], al[4], bh[4], bl[4];
      int g = ks * 4 + l4;
#pragma unroll
      for (int mi = 0; mi < 4; ++mi) {
        int row = wr * 64 + mi * 16 + l15;
        int gp = g ^ (row & 7);
        ah[mi] = *(const bf16x8*)&lds[0][row * 64 + gp * 8];
        al[mi] = *(const bf16x8*)&lds[1][row * 64 + gp * 8];
      }
#pragma unroll
      for (int ni = 0; ni < 4; ++ni) {
        int row = wc * 64 + ni * 16 + l15;
        int gp = g ^ (row & 7);
        bh[ni] = *(const bf16x8*)&lds[2][row * 64 + gp * 8];
        bl[ni] = *(const bf16x8*)&lds[3][row * 64 + gp * 8];
      }
#pragma unroll
      for (int mi = 0; mi < 4; ++mi)
#pragma unroll
        for (int ni = 0; ni < 4; ++ni) {
          acc[mi][ni] = __builtin_amdgcn_mfma_f32_16x16x32_bf16(ah[mi], bh[ni], acc[mi][ni], 0, 0, 0);
          acc[mi][ni] = __builtin_amdgcn_mfma_f32_16x16x32_bf16(al[mi], bh[ni], acc[mi][ni], 0, 0, 0);
          acc[mi][ni] = __builtin_amdgcn_mfma_f32_16x16x32_bf16(ah[mi], bl[ni], acc[mi][ni], 0, 0, 0);
        }
    }
    __syncthreads();
  }

#pragma unroll
  for (int ni = 0; ni < 4; ++ni) {
    int col = colBase + wc * 64 + ni * 16 + l15;
    if (col < NSTORE) {
#pragma unroll
      for (int mi = 0; mi < 4; ++mi) {
        f32x4 v = acc[mi][ni];
#pragma unroll
        for (int i = 0; i < 4; ++i) {
          int r = rowBase + wr * 64 + mi * 16 + l4 * 4 + i;
          if (r < M) {
            if (F16OUT)
              ((unsigned short*)Cout)[((size_t)(col >> 5) * NN + r) * 32 + (col & 31)] = f16u(v[i]);
            else
              ((float*)Cout)[(size_t)r * NSTORE + col] = v[i];
          }
        }
      }
    }
  }
}

// ---------------- chunked XCD-pinned aggregation ----------------
// T chunked [8][NN][32] fp16. chunk = blockIdx&7 -> pinned to one XCD (bid%8 round-robin).
// Block = 4 waves x 16 nodes. Wave: 4 edge-groups of 16 lanes; lane covers 2 cols.

__global__ __launch_bounds__(256) void aggc_kernel(
    const unsigned short* __restrict__ Tc, unsigned short* __restrict__ Phi,
    unsigned short* __restrict__ Plo, const int* __restrict__ rp,
    const int2* __restrict__ ew, const float* __restrict__ dis,
    const float* __restrict__ b) {
  int chunk = blockIdx.x & 7;
  int nb = blockIdx.x >> 3;
  int wave = threadIdx.x >> 6, lane = threadIdx.x & 63;
  int grp = lane >> 4, gl = lane & 15;
  const unsigned short* __restrict__ T = Tc + (size_t)chunk * NN * 32;
  int c0 = 2 * gl;
  float bias0 = b[chunk * 32 + c0], bias1 = b[chunk * 32 + c0 + 1];
#pragma unroll 1
  for (int i = 0; i < 16; ++i) {
    int node = nb * 64 + wave * 16 + i;
    if (node >= NN) continue;
    int beg = rp[node], end = rp[node + 1];
    float a0 = 0.f, a1 = 0.f;
    int e = beg + grp;
    for (; e + 4 < end; e += 8) {
      int2 s0 = ew[e], s1 = ew[e + 4];
      float f0 = __int_as_float(s0.y), f1 = __int_as_float(s1.y);
      ushort2 t0 = *(const ushort2*)&T[(size_t)s0.x * 32 + c0];
      ushort2 t1 = *(const ushort2*)&T[(size_t)s1.x * 32 + c0];
      a0 += f0 * f16f(t0.x) + f1 * f16f(t1.x);
      a1 += f0 * f16f(t0.y) + f1 * f16f(t1.y);
    }
    if (e < end) {
      int2 s0 = ew[e];
      float f0 = __int_as_float(s0.y);
      ushort2 t0 = *(const ushort2*)&T[(size_t)s0.x * 32 + c0];
      a0 += f0 * f16f(t0.x);
      a1 += f0 * f16f(t0.y);
    }
    a0 += __shfl_xor(a0, 16, 64); a1 += __shfl_xor(a1, 16, 64);
    a0 += __shfl_xor(a0, 32, 64); a1 += __shfl_xor(a1, 32, 64);
    if (grp == 0) {
      float d = dis[node];
      float w0 = d * d;
      ushort2 ts = *(const ushort2*)&T[(size_t)node * 32 + c0];
      float v0 = bias0 + a0 + w0 * f16f(ts.x);
      float v1 = bias1 + a1 + w0 * f16f(ts.y);
      v0 = fmaxf(v0, 0.f); v1 = fmaxf(v1, 0.f);
      ushort2 h, l;
      h.x = bf16_rn(v0); l.x = bf16_rn(v0 - bf16f(h.x));
      h.y = bf16_rn(v1); l.y = bf16_rn(v1 - bf16f(h.y));
      size_t oi = (size_t)node * 256 + chunk * 32 + c0;
      *(ushort2*)&Phi[oi] = h;
      *(ushort2*)&Plo[oi] = l;
    }
  }
}

__global__ __launch_bounds__(256) void agg40_kernel(
    const float* __restrict__ T, float* __restrict__ O, const int* __restrict__ rp,
    const int2* __restrict__ ew, const float* __restrict__ dis,
    const float* __restrict__ b) {
  int node = (blockIdx.x * blockDim.x + threadIdx.x) >> 6;
  int lane = threadIdx.x & 63;
  if (node >= NN) return;
  float d = dis[node];
  int e = rp[node], end = rp[node + 1];
  if (lane < NC) {
    float acc = b[lane] + d * d * T[(size_t)node * NC + lane];
    for (; e + 4 <= end; e += 4) {
      int2 e0 = ew[e], e1 = ew[e + 1], e2 = ew[e + 2], e3 = ew[e + 3];
      float t0 = T[(size_t)e0.x * NC + lane];
      float t1 = T[(size_t)e1.x * NC + lane];
      float t2 = T[(size_t)e2.x * NC + lane];
      float t3 = T[(size_t)e3.x * NC + lane];
      acc += __int_as_float(e0.y) * t0 + __int_as_float(e1.y) * t1 +
             __int_as_float(e2.y) * t2 + __int_as_float(e3.y) * t3;
    }
    for (; e < end; ++e) {
      int2 sw = ew[e];
      acc += __int_as_float(sw.y) * T[(size_t)sw.x * NC + lane];
    }
    O[(size_t)node * NC + lane] = acc;
  }
}

// ---------------- launch ----------------

extern "C" void kernel_launch(void* const* d_in, const int* in_sizes, int n_in,
                              void* d_out, int out_size, void* d_ws, size_t ws_size,
                              hipStream_t stream) {
  const float* x  = (const float*)d_in[0];
  const int* edge = (const int*)d_in[1];
  const float* W1 = (const float*)d_in[2];
  const float* b1 = (const float*)d_in[3];
  const float* W2 = (const float*)d_in[4];
  const float* b2 = (const float*)d_in[5];
  const float* W3 = (const float*)d_in[6];
  const float* b3 = (const float*)d_in[7];
  const float* W4 = (const float*)d_in[8];
  const float* b4 = (const float*)d_in[9];
  float* out = (float*)d_out;

  char* p = (char*)d_ws;
  float* T = (float*)p;              p += (size_t)NN * NH * 4;  // fp16 chunked layers 1-3, f32 layer 4
  unsigned short* T16 = (unsigned short*)T;
  unsigned short* Phi = (unsigned short*)p; p += (size_t)NN * NH * 2;
  unsigned short* Plo = (unsigned short*)p; p += (size_t)NN * NH * 2;
  int* cnt = (int*)p;                p += (size_t)NN * 4;
  float* dis = (float*)p;            p += (size_t)NN * 4;
  int* row_ptr = (int*)p;            p += (size_t)(NN + 16) * 4;
  int* cur = (int*)p;                p += (size_t)NN * 4;
  int* bsum = (int*)p;               p += 256 * 4;
  int2* ew = (int2*)p;               p += (size_t)NE * 8;
  unsigned short* W1thi = (unsigned short*)p; p += 256 * 256 * 2;
  unsigned short* W1tlo = (unsigned short*)p; p += 256 * 256 * 2;
  unsigned short* W2thi = (unsigned short*)p; p += 256 * 256 * 2;
  unsigned short* W2tlo = (unsigned short*)p; p += 256 * 256 * 2;
  unsigned short* W3thi = (unsigned short*)p; p += 256 * 256 * 2;
  unsigned short* W3tlo = (unsigned short*)p; p += 256 * 256 * 2;
  unsigned short* W4thi = (unsigned short*)p; p += 128 * 256 * 2;
  unsigned short* W4tlo = (unsigned short*)p; p += 128 * 256 * 2;

  const int* e_src = edge;
  const int* e_dst = edge + NE;

  hipMemsetAsync(cnt, 0, (size_t)NN * 4, stream);
  hipMemsetAsync(cur, 0, (size_t)NN * 4, stream);

  const int nb1024 = (NN + 1023) / 1024;
  count_kernel<<<(NE + 255) / 256, 256, 0, stream>>>(e_dst, cnt);
  dis_kernel<<<(NN + 255) / 256, 256, 0, stream>>>(cnt, dis);
  scan1_kernel<<<nb1024, 1024, 0, stream>>>(cnt, row_ptr, bsum);
  scan2_kernel<<<1, 64, 0, stream>>>(bsum);
  scan3_kernel<<<nb1024, 1024, 0, stream>>>(row_ptr, bsum);
  scatter_kernel<<<(NE + 255) / 256, 256, 0, stream>>>(e_src, e_dst, row_ptr, cur, ew, dis);

  split_kernel<<<(NN * NF / 4 + 255) / 256, 256, 0, stream>>>(x, Phi, Plo);
  wsplit_kernel<<<256, 256, 0, stream>>>(W1, W1thi, W1tlo, NH, 256);
  wsplit_kernel<<<256, 256, 0, stream>>>(W2, W2thi, W2tlo, NH, 256);
  wsplit_kernel<<<256, 256, 0, stream>>>(W3, W3thi, W3tlo, NH, 256);
  wsplit_kernel<<<128, 256, 0, stream>>>(W4, W4thi, W4tlo, NC, 128);

  dim3 gFull((NN + 127) / 128, 2);
  dim3 gLast((NN + 127) / 128, 1);
  int aggcBlocks = 8 * ((NN + 63) / 64);  // 8 chunks x 782 node-blocks
  int agg40Blocks = (NN * 64 + 255) / 256;

  gemm_mfma<256, true><<<gFull, 256, 0, stream>>>(Phi, Plo, W1thi, W1tlo, T16, NN);
  aggc_kernel<<<aggcBlocks, 256, 0, stream>>>(T16, Phi, Plo, row_ptr, ew, dis, b1);
  gemm_mfma<256, true><<<gFull, 256, 0, stream>>>(Phi, Plo, W2thi, W2tlo, T16, NN);
  aggc_kernel<<<aggcBlocks, 256, 0, stream>>>(T16, Phi, Plo, row_ptr, ew, dis, b2);
  gemm_mfma<256, true><<<gFull, 256, 0, stream>>>(Phi, Plo, W3thi, W3tlo, T16, NN);
  aggc_kernel<<<aggcBlocks, 256, 0, stream>>>(T16, Phi, Plo, row_ptr, ew, dis, b3);
  gemm_mfma<NC, false><<<gLast, 256, 0, stream>>>(Phi, Plo, W4thi, W4tlo, T, NN);
  agg40_kernel<<<agg40Blocks, 256, 0, stream>>>(T, out, row_ptr, ew, dis, b4);
}

// Round 7
// 409.918 us; speedup vs baseline: 1.8322x; 1.8322x over previous
//
#include <hip/hip_runtime.h>

#define NN 50000
#define NF 256
#define NH 256
#define NC 40
#define NE 800000

typedef _Float16 f16x8 __attribute__((ext_vector_type(8)));
typedef float f32x4 __attribute__((ext_vector_type(4)));

__device__ __forceinline__ float f16f(unsigned short u) {
  union { unsigned short u; _Float16 h; } a; a.u = u;
  return (float)a.h;
}
__device__ __forceinline__ unsigned short f16u(float f) {
  union { unsigned short u; _Float16 h; } a; a.h = (_Float16)f;
  return a.u;
}

__device__ __forceinline__ void gl16(const void* g, void* l) {
  __builtin_amdgcn_global_load_lds(
      (const __attribute__((address_space(1))) unsigned int*)g,
      (__attribute__((address_space(3))) unsigned int*)l, 16, 0, 0);
}

// ---------------- preprocessing ----------------

__global__ void count_kernel(const int* __restrict__ dst, int* __restrict__ cnt) {
  int e = blockIdx.x * blockDim.x + threadIdx.x;
  if (e < NE) atomicAdd(&cnt[dst[e]], 1);
}

__global__ void dis_kernel(const int* __restrict__ cnt, float* __restrict__ dis) {
  int i = blockIdx.x * blockDim.x + threadIdx.x;
  if (i < NN) dis[i] = rsqrtf((float)(cnt[i] + 1));
}

__global__ __launch_bounds__(1024) void scan1_kernel(const int* __restrict__ cnt,
                                                     int* __restrict__ row_ptr,
                                                     int* __restrict__ bsum) {
  __shared__ int s[1024];
  int i = blockIdx.x * 1024 + threadIdx.x;
  int v = (i < NN) ? cnt[i] : 0;
  s[threadIdx.x] = v;
  __syncthreads();
  for (int ofs = 1; ofs < 1024; ofs <<= 1) {
    int t = (threadIdx.x >= ofs) ? s[threadIdx.x - ofs] : 0;
    __syncthreads();
    s[threadIdx.x] += t;
    __syncthreads();
  }
  if (i < NN) row_ptr[i] = s[threadIdx.x] - v;
  if (threadIdx.x == 1023) bsum[blockIdx.x] = s[1023];
}

__global__ void scan2_kernel(int* __restrict__ bsum) {
  int lane = threadIdx.x;
  const int nb = (NN + 1023) / 1024;
  int v = (lane < nb) ? bsum[lane] : 0;
  for (int ofs = 1; ofs < 64; ofs <<= 1) {
    int t = __shfl_up(v, ofs, 64);
    if (lane >= ofs) v += t;
  }
  if (lane < nb) bsum[lane] = v;
}

__global__ __launch_bounds__(1024) void scan3_kernel(int* __restrict__ row_ptr,
                                                     const int* __restrict__ bsum) {
  int i = blockIdx.x * 1024 + threadIdx.x;
  int add = (blockIdx.x > 0) ? bsum[blockIdx.x - 1] : 0;
  if (i < NN) row_ptr[i] += add;
  if (i == 0) row_ptr[NN] = NE;
}

__global__ void scatter_kernel(const int* __restrict__ src, const int* __restrict__ dst,
                               const int* __restrict__ row_ptr, int* __restrict__ cur,
                               int2* __restrict__ ew, const float* __restrict__ dis) {
  int e = blockIdx.x * blockDim.x + threadIdx.x;
  if (e < NE) {
    int d = dst[e], s = src[e];
    int pos = row_ptr[d] + atomicAdd(&cur[d], 1);
    int2 v; v.x = s; v.y = __float_as_int(dis[s] * dis[d]);
    ew[pos] = v;
  }
}

// ---------------- conversions ----------------

// x (f32) -> single fp16 plane
__global__ __launch_bounds__(256) void xf16_kernel(const float* __restrict__ x,
                                                   unsigned short* __restrict__ P) {
  int i = blockIdx.x * blockDim.x + threadIdx.x;
  if (i >= NN * NF / 4) return;
  float4 v = ((const float4*)x)[i];
  ushort4 h;
  h.x = f16u(v.x); h.y = f16u(v.y); h.z = f16u(v.z); h.w = f16u(v.w);
  ((ushort4*)P)[i] = h;
}

// W[K=256][N] -> Wt fp16 hi/lo [NT][256], zero-padded rows n>=N
__global__ void wsplit_kernel(const float* __restrict__ W,
                              unsigned short* __restrict__ Whi,
                              unsigned short* __restrict__ Wlo, int N, int NT) {
  int idx = blockIdx.x * blockDim.x + threadIdx.x;
  if (idx >= NT * 256) return;
  int n = idx >> 8, k = idx & 255;
  float v = (n < N) ? W[k * N + n] : 0.0f;
  unsigned short h = f16u(v);
  Whi[idx] = h;
  Wlo[idx] = f16u(v - f16f(h));
}

// ---------------- fp16 MFMA GEMM: C[M][NSTORE] = A[M][256] * Bt[*][256]^T ----------------
// A: single fp16 plane. B: fp16 hi+lo (2 MFMA passes). Output fp16.

template <int NSTORE>
__global__ __launch_bounds__(256, 2) void gemm_f16(
    const unsigned short* __restrict__ A,
    const unsigned short* __restrict__ Bthi, const unsigned short* __restrict__ Btlo,
    unsigned short* __restrict__ Cout, int M) {
  __shared__ unsigned short lds[3][128 * 64];  // A, Bhi, Blo tiles (16 KB each)

  int tid = threadIdx.x;
  int rowBase = blockIdx.x * 128;
  int colBase = blockIdx.y * 128;
  int w = tid >> 6, lane = tid & 63;
  int wr = w >> 1, wc = w & 1;
  int l15 = lane & 15, l4 = lane >> 4;

  f32x4 acc[4][4] = {};

  for (int kt = 0; kt < 4; ++kt) {
#pragma unroll
    for (int c = 0; c < 4; ++c) {
      int gi = c * 256 + tid;
      int row = gi >> 3, gp = gi & 7;
      int gsrc = gp ^ (row & 7);
      int ar = rowBase + row; ar = ar < M ? ar : M - 1;
      int koff = kt * 64 + gsrc * 8;
      gl16(A + (size_t)ar * 256 + koff, &lds[0][gi * 8]);
      int br = colBase + row;
      gl16(Bthi + (size_t)br * 256 + koff, &lds[1][gi * 8]);
      gl16(Btlo + (size_t)br * 256 + koff, &lds[2][gi * 8]);
    }
    __syncthreads();

#pragma unroll
    for (int ks = 0; ks < 2; ++ks) {
      f16x8 a[4], bh[4], bl[4];
      int g = ks * 4 + l4;
#pragma unroll
      for (int mi = 0; mi < 4; ++mi) {
        int row = wr * 64 + mi * 16 + l15;
        int gp = g ^ (row & 7);
        a[mi] = *(const f16x8*)&lds[0][row * 64 + gp * 8];
      }
#pragma unroll
      for (int ni = 0; ni < 4; ++ni) {
        int row = wc * 64 + ni * 16 + l15;
        int gp = g ^ (row & 7);
        bh[ni] = *(const f16x8*)&lds[1][row * 64 + gp * 8];
        bl[ni] = *(const f16x8*)&lds[2][row * 64 + gp * 8];
      }
#pragma unroll
      for (int mi = 0; mi < 4; ++mi)
#pragma unroll
        for (int ni = 0; ni < 4; ++ni) {
          acc[mi][ni] = __builtin_amdgcn_mfma_f32_16x16x32_f16(a[mi], bh[ni], acc[mi][ni], 0, 0, 0);
          acc[mi][ni] = __builtin_amdgcn_mfma_f32_16x16x32_f16(a[mi], bl[ni], acc[mi][ni], 0, 0, 0);
        }
    }
    __syncthreads();
  }

  // epilogue: D row=(lane>>4)*4+i, col=lane&15 (m89 layout), fp16 store
#pragma unroll
  for (int ni = 0; ni < 4; ++ni) {
    int col = colBase + wc * 64 + ni * 16 + l15;
    if (col < NSTORE) {
#pragma unroll
      for (int mi = 0; mi < 4; ++mi) {
        f32x4 v = acc[mi][ni];
#pragma unroll
        for (int i = 0; i < 4; ++i) {
          int r = rowBase + wr * 64 + mi * 16 + l4 * 4 + i;
          if (r < M) Cout[(size_t)r * NSTORE + col] = f16u(v[i]);
        }
      }
    }
  }
}

// ---------------- aggregation: one wave per node, fp16 T in / fp16 P out ----------------

__global__ __launch_bounds__(256) void agg256_kernel(
    const unsigned short* __restrict__ T, unsigned short* __restrict__ P,
    const int* __restrict__ rp, const int2* __restrict__ ew,
    const float* __restrict__ dis, const float* __restrict__ b) {
  int node = (blockIdx.x * blockDim.x + threadIdx.x) >> 6;
  int lane = threadIdx.x & 63;
  if (node >= NN) return;
  const ushort4* Tv = (const ushort4*)T;  // row = 64 ushort4s (256 fp16)
  float4 bv = ((const float4*)b)[lane];
  float d = dis[node];
  float w0 = d * d;
  ushort4 t = Tv[(size_t)node * 64 + lane];
  float ax = bv.x + w0 * f16f(t.x), ay = bv.y + w0 * f16f(t.y);
  float az = bv.z + w0 * f16f(t.z), aw = bv.w + w0 * f16f(t.w);
  int e = rp[node], end = rp[node + 1];
  for (; e + 4 <= end; e += 4) {
    int2 e0 = ew[e], e1 = ew[e + 1], e2 = ew[e + 2], e3 = ew[e + 3];
    ushort4 t0 = Tv[(size_t)e0.x * 64 + lane];
    ushort4 t1 = Tv[(size_t)e1.x * 64 + lane];
    ushort4 t2 = Tv[(size_t)e2.x * 64 + lane];
    ushort4 t3 = Tv[(size_t)e3.x * 64 + lane];
    float f0 = __int_as_float(e0.y), f1 = __int_as_float(e1.y);
    float f2 = __int_as_float(e2.y), f3 = __int_as_float(e3.y);
    ax += f0 * f16f(t0.x) + f1 * f16f(t1.x) + f2 * f16f(t2.x) + f3 * f16f(t3.x);
    ay += f0 * f16f(t0.y) + f1 * f16f(t1.y) + f2 * f16f(t2.y) + f3 * f16f(t3.y);
    az += f0 * f16f(t0.z) + f1 * f16f(t1.z) + f2 * f16f(t2.z) + f3 * f16f(t3.z);
    aw += f0 * f16f(t0.w) + f1 * f16f(t1.w) + f2 * f16f(t2.w) + f3 * f16f(t3.w);
  }
  for (; e < end; ++e) {
    int2 sw = ew[e];
    float f = __int_as_float(sw.y);
    ushort4 ts = Tv[(size_t)sw.x * 64 + lane];
    ax += f * f16f(ts.x); ay += f * f16f(ts.y);
    az += f * f16f(ts.z); aw += f * f16f(ts.w);
  }
  ax = fmaxf(ax, 0.f); ay = fmaxf(ay, 0.f);
  az = fmaxf(az, 0.f); aw = fmaxf(aw, 0.f);
  ushort4 h;
  h.x = f16u(ax); h.y = f16u(ay); h.z = f16u(az); h.w = f16u(aw);
  ((ushort4*)P)[(size_t)node * 64 + lane] = h;
}

__global__ __launch_bounds__(256) void agg40_kernel(
    const unsigned short* __restrict__ T, float* __restrict__ O,
    const int* __restrict__ rp, const int2* __restrict__ ew,
    const float* __restrict__ dis, const float* __restrict__ b) {
  int node = (blockIdx.x * blockDim.x + threadIdx.x) >> 6;
  int lane = threadIdx.x & 63;
  if (node >= NN) return;
  float d = dis[node];
  int e = rp[node], end = rp[node + 1];
  if (lane < NC) {
    float acc = b[lane] + d * d * f16f(T[(size_t)node * NC + lane]);
    for (; e + 4 <= end; e += 4) {
      int2 e0 = ew[e], e1 = ew[e + 1], e2 = ew[e + 2], e3 = ew[e + 3];
      float t0 = f16f(T[(size_t)e0.x * NC + lane]);
      float t1 = f16f(T[(size_t)e1.x * NC + lane]);
      float t2 = f16f(T[(size_t)e2.x * NC + lane]);
      float t3 = f16f(T[(size_t)e3.x * NC + lane]);
      acc += __int_as_float(e0.y) * t0 + __int_as_float(e1.y) * t1 +
             __int_as_float(e2.y) * t2 + __int_as_float(e3.y) * t3;
    }
    for (; e < end; ++e) {
      int2 sw = ew[e];
      acc += __int_as_float(sw.y) * f16f(T[(size_t)sw.x * NC + lane]);
    }
    O[(size_t)node * NC + lane] = acc;
  }
}

// ---------------- launch ----------------

extern "C" void kernel_launch(void* const* d_in, const int* in_sizes, int n_in,
                              void* d_out, int out_size, void* d_ws, size_t ws_size,
                              hipStream_t stream) {
  const float* x  = (const float*)d_in[0];
  const int* edge = (const int*)d_in[1];
  const float* W1 = (const float*)d_in[2];
  const float* b1 = (const float*)d_in[3];
  const float* W2 = (const float*)d_in[4];
  const float* b2 = (const float*)d_in[5];
  const float* W3 = (const float*)d_in[6];
  const float* b3 = (const float*)d_in[7];
  const float* W4 = (const float*)d_in[8];
  const float* b4 = (const float*)d_in[9];
  float* out = (float*)d_out;

  char* p = (char*)d_ws;
  unsigned short* T16 = (unsigned short*)p; p += (size_t)NN * NH * 2;  // 25.6 MB
  unsigned short* P16 = (unsigned short*)p; p += (size_t)NN * NH * 2;  // 25.6 MB
  int* cnt = (int*)p;                p += (size_t)NN * 4;
  float* dis = (float*)p;            p += (size_t)NN * 4;
  int* row_ptr = (int*)p;            p += (size_t)(NN + 16) * 4;
  int* cur = (int*)p;                p += (size_t)NN * 4;
  int* bsum = (int*)p;               p += 256 * 4;
  int2* ew = (int2*)p;               p += (size_t)NE * 8;
  unsigned short* W1thi = (unsigned short*)p; p += 256 * 256 * 2;
  unsigned short* W1tlo = (unsigned short*)p; p += 256 * 256 * 2;
  unsigned short* W2thi = (unsigned short*)p; p += 256 * 256 * 2;
  unsigned short* W2tlo = (unsigned short*)p; p += 256 * 256 * 2;
  unsigned short* W3thi = (unsigned short*)p; p += 256 * 256 * 2;
  unsigned short* W3tlo = (unsigned short*)p; p += 256 * 256 * 2;
  unsigned short* W4thi = (unsigned short*)p; p += 128 * 256 * 2;
  unsigned short* W4tlo = (unsigned short*)p; p += 128 * 256 * 2;

  const int* e_src = edge;
  const int* e_dst = edge + NE;

  hipMemsetAsync(cnt, 0, (size_t)NN * 4, stream);
  hipMemsetAsync(cur, 0, (size_t)NN * 4, stream);

  const int nb1024 = (NN + 1023) / 1024;
  count_kernel<<<(NE + 255) / 256, 256, 0, stream>>>(e_dst, cnt);
  dis_kernel<<<(NN + 255) / 256, 256, 0, stream>>>(cnt, dis);
  scan1_kernel<<<nb1024, 1024, 0, stream>>>(cnt, row_ptr, bsum);
  scan2_kernel<<<1, 64, 0, stream>>>(bsum);
  scan3_kernel<<<nb1024, 1024, 0, stream>>>(row_ptr, bsum);
  scatter_kernel<<<(NE + 255) / 256, 256, 0, stream>>>(e_src, e_dst, row_ptr, cur, ew, dis);

  xf16_kernel<<<(NN * NF / 4 + 255) / 256, 256, 0, stream>>>(x, P16);
  wsplit_kernel<<<256, 256, 0, stream>>>(W1, W1thi, W1tlo, NH, 256);
  wsplit_kernel<<<256, 256, 0, stream>>>(W2, W2thi, W2tlo, NH, 256);
  wsplit_kernel<<<256, 256, 0, stream>>>(W3, W3thi, W3tlo, NH, 256);
  wsplit_kernel<<<128, 256, 0, stream>>>(W4, W4thi, W4tlo, NC, 128);

  dim3 gFull((NN + 127) / 128, 2);
  dim3 gLast((NN + 127) / 128, 1);
  int aggBlocks = (NN * 64 + 255) / 256;

  gemm_f16<256><<<gFull, 256, 0, stream>>>(P16, W1thi, W1tlo, T16, NN);
  agg256_kernel<<<aggBlocks, 256, 0, stream>>>(T16, P16, row_ptr, ew, dis, b1);
  gemm_f16<256><<<gFull, 256, 0, stream>>>(P16, W2thi, W2tlo, T16, NN);
  agg256_kernel<<<aggBlocks, 256, 0, stream>>>(T16, P16, row_ptr, ew, dis, b2);
  gemm_f16<256><<<gFull, 256, 0, stream>>>(P16, W3thi, W3tlo, T16, NN);
  agg256_kernel<<<aggBlocks, 256, 0, stream>>>(T16, P16, row_ptr, ew, dis, b3);
  gemm_f16<NC><<<gLast, 256, 0, stream>>>(P16, W4thi, W4tlo, T16, NN);
  agg40_kernel<<<aggBlocks, 256, 0, stream>>>(T16, out, row_ptr, ew, dis, b4);
}

// Round 8
// 381.867 us; speedup vs baseline: 1.9668x; 1.0735x over previous
//
#include <hip/hip_runtime.h>

#define NN 50000
#define NF 256
#define NH 256
#define NC 40
#define NE 800000

typedef _Float16 f16x8 __attribute__((ext_vector_type(8)));
typedef float f32x4 __attribute__((ext_vector_type(4)));

__device__ __forceinline__ float f16f(unsigned short u) {
  union { unsigned short u; _Float16 h; } a; a.u = u;
  return (float)a.h;
}
__device__ __forceinline__ unsigned short f16u(float f) {
  union { unsigned short u; _Float16 h; } a; a.h = (_Float16)f;
  return a.u;
}

__device__ __forceinline__ void gl16(const void* g, void* l) {
  __builtin_amdgcn_global_load_lds(
      (const __attribute__((address_space(1))) unsigned int*)g,
      (__attribute__((address_space(3))) unsigned int*)l, 16, 0, 0);
}

// ---------------- preprocessing ----------------

__global__ void count_kernel(const int* __restrict__ dst, int* __restrict__ cnt) {
  int e = blockIdx.x * blockDim.x + threadIdx.x;
  if (e < NE) atomicAdd(&cnt[dst[e]], 1);
}

// per-block scan of cnt -> row_ptr (exclusive within block) + bsum; also dis = rsqrt(cnt+1)
__global__ __launch_bounds__(1024) void scan1_kernel(const int* __restrict__ cnt,
                                                     int* __restrict__ row_ptr,
                                                     int* __restrict__ bsum,
                                                     float* __restrict__ dis) {
  __shared__ int s[1024];
  int i = blockIdx.x * 1024 + threadIdx.x;
  int v = (i < NN) ? cnt[i] : 0;
  if (i < NN) dis[i] = rsqrtf((float)(v + 1));
  s[threadIdx.x] = v;
  __syncthreads();
  for (int ofs = 1; ofs < 1024; ofs <<= 1) {
    int t = (threadIdx.x >= ofs) ? s[threadIdx.x - ofs] : 0;
    __syncthreads();
    s[threadIdx.x] += t;
    __syncthreads();
  }
  if (i < NN) row_ptr[i] = s[threadIdx.x] - v;
  if (threadIdx.x == 1023) bsum[blockIdx.x] = s[1023];
}

// merged: wave-scan of bsum (redundant per block) + add offsets
__global__ __launch_bounds__(1024) void scan23_kernel(int* __restrict__ row_ptr,
                                                      const int* __restrict__ bsum) {
  __shared__ int sb[64];
  const int nb = (NN + 1023) / 1024;  // 49
  if (threadIdx.x < 64) {
    int lane = threadIdx.x;
    int v = (lane < nb) ? bsum[lane] : 0;
    for (int ofs = 1; ofs < 64; ofs <<= 1) {
      int t = __shfl_up(v, ofs, 64);
      if (lane >= ofs) v += t;
    }
    sb[lane] = v;  // inclusive
  }
  __syncthreads();
  int i = blockIdx.x * 1024 + threadIdx.x;
  int add = (blockIdx.x > 0) ? sb[blockIdx.x - 1] : 0;
  if (i < NN) row_ptr[i] += add;
  if (i == 0) row_ptr[NN] = NE;
}

__global__ void scatter_kernel(const int* __restrict__ src, const int* __restrict__ dst,
                               const int* __restrict__ row_ptr, int* __restrict__ cur,
                               int2* __restrict__ ew, const float* __restrict__ dis) {
  int e = blockIdx.x * blockDim.x + threadIdx.x;
  if (e < NE) {
    int d = dst[e], s = src[e];
    int pos = row_ptr[d] + atomicAdd(&cur[d], 1);
    int2 v; v.x = s; v.y = __float_as_int(dis[s] * dis[d]);
    ew[pos] = v;
  }
}

// ---------------- conversions ----------------

// x (f32) -> single fp16 plane
__global__ __launch_bounds__(256) void xf16_kernel(const float* __restrict__ x,
                                                   unsigned short* __restrict__ P) {
  int i = blockIdx.x * blockDim.x + threadIdx.x;
  if (i >= NN * NF / 4) return;
  float4 v = ((const float4*)x)[i];
  ushort4 h;
  h.x = f16u(v.x); h.y = f16u(v.y); h.z = f16u(v.z); h.w = f16u(v.w);
  ((ushort4*)P)[i] = h;
}

// all four weights: W[K=256][N] -> Wt fp16 [NT][256] (transposed, zero-padded)
__global__ void wf16_kernel(const float* __restrict__ W1, const float* __restrict__ W2,
                            const float* __restrict__ W3, const float* __restrict__ W4,
                            unsigned short* __restrict__ Wt1, unsigned short* __restrict__ Wt2,
                            unsigned short* __restrict__ Wt3, unsigned short* __restrict__ Wt4) {
  int idx = blockIdx.x * blockDim.x + threadIdx.x;
  const float* W; unsigned short* Wt; int N;
  if (idx < 65536)       { W = W1; Wt = Wt1; N = 256; }
  else if (idx < 131072) { W = W2; Wt = Wt2; N = 256; idx -= 65536; }
  else if (idx < 196608) { W = W3; Wt = Wt3; N = 256; idx -= 131072; }
  else if (idx < 229376) { W = W4; Wt = Wt4; N = 40;  idx -= 196608; }
  else return;
  int n = idx >> 8, k = idx & 255;
  float v = (n < N) ? W[k * N + n] : 0.0f;
  Wt[idx] = f16u(v);
}

// ---------------- fp16 MFMA GEMM: C[M][NSTORE] = A[M][256] * Bt[*][256]^T ----------------
// A, B single fp16 planes. Output fp16.

template <int NSTORE>
__global__ __launch_bounds__(256, 2) void gemm_f16(
    const unsigned short* __restrict__ A, const unsigned short* __restrict__ Bt,
    unsigned short* __restrict__ Cout, int M) {
  __shared__ unsigned short lds[2][128 * 64];  // A, B tiles (16 KB each)

  int tid = threadIdx.x;
  int rowBase = blockIdx.x * 128;
  int colBase = blockIdx.y * 128;
  int w = tid >> 6, lane = tid & 63;
  int wr = w >> 1, wc = w & 1;
  int l15 = lane & 15, l4 = lane >> 4;

  f32x4 acc[4][4] = {};

  for (int kt = 0; kt < 4; ++kt) {
#pragma unroll
    for (int c = 0; c < 4; ++c) {
      int gi = c * 256 + tid;
      int row = gi >> 3, gp = gi & 7;
      int gsrc = gp ^ (row & 7);
      int ar = rowBase + row; ar = ar < M ? ar : M - 1;
      int koff = kt * 64 + gsrc * 8;
      gl16(A + (size_t)ar * 256 + koff, &lds[0][gi * 8]);
      int br = colBase + row;
      gl16(Bt + (size_t)br * 256 + koff, &lds[1][gi * 8]);
    }
    __syncthreads();

#pragma unroll
    for (int ks = 0; ks < 2; ++ks) {
      f16x8 a[4], b[4];
      int g = ks * 4 + l4;
#pragma unroll
      for (int mi = 0; mi < 4; ++mi) {
        int row = wr * 64 + mi * 16 + l15;
        int gp = g ^ (row & 7);
        a[mi] = *(const f16x8*)&lds[0][row * 64 + gp * 8];
      }
#pragma unroll
      for (int ni = 0; ni < 4; ++ni) {
        int row = wc * 64 + ni * 16 + l15;
        int gp = g ^ (row & 7);
        b[ni] = *(const f16x8*)&lds[1][row * 64 + gp * 8];
      }
#pragma unroll
      for (int mi = 0; mi < 4; ++mi)
#pragma unroll
        for (int ni = 0; ni < 4; ++ni)
          acc[mi][ni] = __builtin_amdgcn_mfma_f32_16x16x32_f16(a[mi], b[ni], acc[mi][ni], 0, 0, 0);
    }
    __syncthreads();
  }

  // epilogue: D row=(lane>>4)*4+i, col=lane&15 (m89 layout), fp16 store
#pragma unroll
  for (int ni = 0; ni < 4; ++ni) {
    int col = colBase + wc * 64 + ni * 16 + l15;
    if (col < NSTORE) {
#pragma unroll
      for (int mi = 0; mi < 4; ++mi) {
        f32x4 v = acc[mi][ni];
#pragma unroll
        for (int i = 0; i < 4; ++i) {
          int r = rowBase + wr * 64 + mi * 16 + l4 * 4 + i;
          if (r < M) Cout[(size_t)r * NSTORE + col] = f16u(v[i]);
        }
      }
    }
  }
}

// ---------------- aggregation: one wave per node, fp16 T in / fp16 P out ----------------

__global__ __launch_bounds__(256) void agg256_kernel(
    const unsigned short* __restrict__ T, unsigned short* __restrict__ P,
    const int* __restrict__ rp, const int2* __restrict__ ew,
    const float* __restrict__ dis, const float* __restrict__ b) {
  int node = (blockIdx.x * blockDim.x + threadIdx.x) >> 6;
  int lane = threadIdx.x & 63;
  if (node >= NN) return;
  const ushort4* Tv = (const ushort4*)T;  // row = 64 ushort4s (256 fp16)
  float4 bv = ((const float4*)b)[lane];
  float d = dis[node];
  float w0 = d * d;
  ushort4 t = Tv[(size_t)node * 64 + lane];
  float ax = bv.x + w0 * f16f(t.x), ay = bv.y + w0 * f16f(t.y);
  float az = bv.z + w0 * f16f(t.z), aw = bv.w + w0 * f16f(t.w);
  int e = rp[node], end = rp[node + 1];
  for (; e + 4 <= end; e += 4) {
    int2 e0 = ew[e], e1 = ew[e + 1], e2 = ew[e + 2], e3 = ew[e + 3];
    ushort4 t0 = Tv[(size_t)e0.x * 64 + lane];
    ushort4 t1 = Tv[(size_t)e1.x * 64 + lane];
    ushort4 t2 = Tv[(size_t)e2.x * 64 + lane];
    ushort4 t3 = Tv[(size_t)e3.x * 64 + lane];
    float f0 = __int_as_float(e0.y), f1 = __int_as_float(e1.y);
    float f2 = __int_as_float(e2.y), f3 = __int_as_float(e3.y);
    ax += f0 * f16f(t0.x) + f1 * f16f(t1.x) + f2 * f16f(t2.x) + f3 * f16f(t3.x);
    ay += f0 * f16f(t0.y) + f1 * f16f(t1.y) + f2 * f16f(t2.y) + f3 * f16f(t3.y);
    az += f0 * f16f(t0.z) + f1 * f16f(t1.z) + f2 * f16f(t2.z) + f3 * f16f(t3.z);
    aw += f0 * f16f(t0.w) + f1 * f16f(t1.w) + f2 * f16f(t2.w) + f3 * f16f(t3.w);
  }
  for (; e < end; ++e) {
    int2 sw = ew[e];
    float f = __int_as_float(sw.y);
    ushort4 ts = Tv[(size_t)sw.x * 64 + lane];
    ax += f * f16f(ts.x); ay += f * f16f(ts.y);
    az += f * f16f(ts.z); aw += f * f16f(ts.w);
  }
  ax = fmaxf(ax, 0.f); ay = fmaxf(ay, 0.f);
  az = fmaxf(az, 0.f); aw = fmaxf(aw, 0.f);
  ushort4 h;
  h.x = f16u(ax); h.y = f16u(ay); h.z = f16u(az); h.w = f16u(aw);
  ((ushort4*)P)[(size_t)node * 64 + lane] = h;
}

__global__ __launch_bounds__(256) void agg40_kernel(
    const unsigned short* __restrict__ T, float* __restrict__ O,
    const int* __restrict__ rp, const int2* __restrict__ ew,
    const float* __restrict__ dis, const float* __restrict__ b) {
  int node = (blockIdx.x * blockDim.x + threadIdx.x) >> 6;
  int lane = threadIdx.x & 63;
  if (node >= NN) return;
  float d = dis[node];
  int e = rp[node], end = rp[node + 1];
  if (lane < NC) {
    float acc = b[lane] + d * d * f16f(T[(size_t)node * NC + lane]);
    for (; e + 4 <= end; e += 4) {
      int2 e0 = ew[e], e1 = ew[e + 1], e2 = ew[e + 2], e3 = ew[e + 3];
      float t0 = f16f(T[(size_t)e0.x * NC + lane]);
      float t1 = f16f(T[(size_t)e1.x * NC + lane]);
      float t2 = f16f(T[(size_t)e2.x * NC + lane]);
      float t3 = f16f(T[(size_t)e3.x * NC + lane]);
      acc += __int_as_float(e0.y) * t0 + __int_as_float(e1.y) * t1 +
             __int_as_float(e2.y) * t2 + __int_as_float(e3.y) * t3;
    }
    for (; e < end; ++e) {
      int2 sw = ew[e];
      acc += __int_as_float(sw.y) * f16f(T[(size_t)sw.x * NC + lane]);
    }
    O[(size_t)node * NC + lane] = acc;
  }
}

// ---------------- launch ----------------

extern "C" void kernel_launch(void* const* d_in, const int* in_sizes, int n_in,
                              void* d_out, int out_size, void* d_ws, size_t ws_size,
                              hipStream_t stream) {
  const float* x  = (const float*)d_in[0];
  const int* edge = (const int*)d_in[1];
  const float* W1 = (const float*)d_in[2];
  const float* b1 = (const float*)d_in[3];
  const float* W2 = (const float*)d_in[4];
  const float* b2 = (const float*)d_in[5];
  const float* W3 = (const float*)d_in[6];
  const float* b3 = (const float*)d_in[7];
  const float* W4 = (const float*)d_in[8];
  const float* b4 = (const float*)d_in[9];
  float* out = (float*)d_out;

  char* p = (char*)d_ws;
  unsigned short* T16 = (unsigned short*)p; p += (size_t)NN * NH * 2;  // 25.6 MB
  unsigned short* P16 = (unsigned short*)p; p += (size_t)NN * NH * 2;  // 25.6 MB
  int* cnt = (int*)p;                p += (size_t)NN * 4;
  int* cur = (int*)p;                p += (size_t)NN * 4;   // adjacent to cnt: one memset
  float* dis = (float*)p;            p += (size_t)NN * 4;
  int* row_ptr = (int*)p;            p += (size_t)(NN + 16) * 4;
  int* bsum = (int*)p;               p += 256 * 4;
  int2* ew = (int2*)p;               p += (size_t)NE * 8;
  unsigned short* Wt1 = (unsigned short*)p; p += 256 * 256 * 2;
  unsigned short* Wt2 = (unsigned short*)p; p += 256 * 256 * 2;
  unsigned short* Wt3 = (unsigned short*)p; p += 256 * 256 * 2;
  unsigned short* Wt4 = (unsigned short*)p; p += 128 * 256 * 2;

  const int* e_src = edge;
  const int* e_dst = edge + NE;

  hipMemsetAsync(cnt, 0, (size_t)NN * 8, stream);  // cnt + cur

  const int nb1024 = (NN + 1023) / 1024;
  count_kernel<<<(NE + 255) / 256, 256, 0, stream>>>(e_dst, cnt);
  scan1_kernel<<<nb1024, 1024, 0, stream>>>(cnt, row_ptr, bsum, dis);
  scan23_kernel<<<nb1024, 1024, 0, stream>>>(row_ptr, bsum);
  scatter_kernel<<<(NE + 255) / 256, 256, 0, stream>>>(e_src, e_dst, row_ptr, cur, ew, dis);

  xf16_kernel<<<(NN * NF / 4 + 255) / 256, 256, 0, stream>>>(x, P16);
  wf16_kernel<<<(229376 + 255) / 256, 256, 0, stream>>>(W1, W2, W3, W4, Wt1, Wt2, Wt3, Wt4);

  dim3 gFull((NN + 127) / 128, 2);
  dim3 gLast((NN + 127) / 128, 1);
  int aggBlocks = (NN * 64 + 255) / 256;

  gemm_f16<256><<<gFull, 256, 0, stream>>>(P16, Wt1, T16, NN);
  agg256_kernel<<<aggBlocks, 256, 0, stream>>>(T16, P16, row_ptr, ew, dis, b1);
  gemm_f16<256><<<gFull, 256, 0, stream>>>(P16, Wt2, T16, NN);
  agg256_kernel<<<aggBlocks, 256, 0, stream>>>(T16, P16, row_ptr, ew, dis, b2);
  gemm_f16<256><<<gFull, 256, 0, stream>>>(P16, Wt3, T16, NN);
  agg256_kernel<<<aggBlocks, 256, 0, stream>>>(T16, P16, row_ptr, ew, dis, b3);
  gemm_f16<NC><<<gLast, 256, 0, stream>>>(P16, Wt4, T16, NN);
  agg40_kernel<<<aggBlocks, 256, 0, stream>>>(T16, out, row_ptr, ew, dis, b4);
}

// Round 9
// 378.736 us; speedup vs baseline: 1.9830x; 1.0083x over previous
//
#include <hip/hip_runtime.h>

#define NN 50000
#define NF 256
#define NH 256
#define NC 40
#define NE 800000

typedef _Float16 f16x8 __attribute__((ext_vector_type(8)));
typedef float f32x4 __attribute__((ext_vector_type(4)));

__device__ __forceinline__ float f16f(unsigned short u) {
  union { unsigned short u; _Float16 h; } a; a.u = u;
  return (float)a.h;
}
__device__ __forceinline__ unsigned short f16u(float f) {
  union { unsigned short u; _Float16 h; } a; a.h = (_Float16)f;
  return a.u;
}

__device__ __forceinline__ void gl16(const void* g, void* l) {
  __builtin_amdgcn_global_load_lds(
      (const __attribute__((address_space(1))) unsigned int*)g,
      (__attribute__((address_space(3))) unsigned int*)l, 16, 0, 0);
}

// ---------------- preprocessing ----------------

__global__ void count_kernel(const int* __restrict__ dst, int* __restrict__ cnt) {
  int e = blockIdx.x * blockDim.x + threadIdx.x;
  if (e < NE) atomicAdd(&cnt[dst[e]], 1);
}

__global__ __launch_bounds__(1024) void scan1_kernel(const int* __restrict__ cnt,
                                                     int* __restrict__ row_ptr,
                                                     int* __restrict__ bsum,
                                                     float* __restrict__ dis) {
  __shared__ int s[1024];
  int i = blockIdx.x * 1024 + threadIdx.x;
  int v = (i < NN) ? cnt[i] : 0;
  if (i < NN) dis[i] = rsqrtf((float)(v + 1));
  s[threadIdx.x] = v;
  __syncthreads();
  for (int ofs = 1; ofs < 1024; ofs <<= 1) {
    int t = (threadIdx.x >= ofs) ? s[threadIdx.x - ofs] : 0;
    __syncthreads();
    s[threadIdx.x] += t;
    __syncthreads();
  }
  if (i < NN) row_ptr[i] = s[threadIdx.x] - v;
  if (threadIdx.x == 1023) bsum[blockIdx.x] = s[1023];
}

__global__ __launch_bounds__(1024) void scan23_kernel(int* __restrict__ row_ptr,
                                                      const int* __restrict__ bsum) {
  __shared__ int sb[64];
  const int nb = (NN + 1023) / 1024;  // 49
  if (threadIdx.x < 64) {
    int lane = threadIdx.x;
    int v = (lane < nb) ? bsum[lane] : 0;
    for (int ofs = 1; ofs < 64; ofs <<= 1) {
      int t = __shfl_up(v, ofs, 64);
      if (lane >= ofs) v += t;
    }
    sb[lane] = v;
  }
  __syncthreads();
  int i = blockIdx.x * 1024 + threadIdx.x;
  int add = (blockIdx.x > 0) ? sb[blockIdx.x - 1] : 0;
  if (i < NN) row_ptr[i] += add;
  if (i == 0) row_ptr[NN] = NE;
}

__global__ void scatter_kernel(const int* __restrict__ src, const int* __restrict__ dst,
                               const int* __restrict__ row_ptr, int* __restrict__ cur,
                               int2* __restrict__ ew, const float* __restrict__ dis) {
  int e = blockIdx.x * blockDim.x + threadIdx.x;
  if (e < NE) {
    int d = dst[e], s = src[e];
    int pos = row_ptr[d] + atomicAdd(&cur[d], 1);
    int2 v; v.x = s; v.y = __float_as_int(dis[s] * dis[d]);
    ew[pos] = v;
  }
}

// ---------------- weight conversion ----------------

__global__ void wf16_kernel(const float* __restrict__ W1, const float* __restrict__ W2,
                            const float* __restrict__ W3, const float* __restrict__ W4,
                            unsigned short* __restrict__ Wt1, unsigned short* __restrict__ Wt2,
                            unsigned short* __restrict__ Wt3, unsigned short* __restrict__ Wt4) {
  int idx = blockIdx.x * blockDim.x + threadIdx.x;
  const float* W; unsigned short* Wt; int N;
  if (idx < 65536)       { W = W1; Wt = Wt1; N = 256; }
  else if (idx < 131072) { W = W2; Wt = Wt2; N = 256; idx -= 65536; }
  else if (idx < 196608) { W = W3; Wt = Wt3; N = 256; idx -= 131072; }
  else if (idx < 229376) { W = W4; Wt = Wt4; N = 40;  idx -= 196608; }
  else return;
  int n = idx >> 8, k = idx & 255;
  float v = (n < N) ? W[k * N + n] : 0.0f;
  Wt[idx] = f16u(v);
}

// ---------------- fp16 MFMA GEMM, 2-phase double-buffered staging ----------------
// C[M][NSTORE] = A[M][256] * Bt[*][256]^T. AF32: A is f32 (reg-staged + converted).

template <int NSTORE, bool AF32>
__global__ __launch_bounds__(256, 2) void gemm_f16(
    const void* __restrict__ Ain, const unsigned short* __restrict__ Bt,
    unsigned short* __restrict__ Cout, int M) {
  __shared__ unsigned short lds[2][2][128 * 64];  // [buf][A/B] 16 KB planes

  int tid = threadIdx.x;
  int rowBase = blockIdx.x * 128;
  int colBase = blockIdx.y * 128;
  int w = tid >> 6, lane = tid & 63;
  int wr = w >> 1, wc = w & 1;
  int l15 = lane & 15, l4 = lane >> 4;

  f32x4 acc[4][4] = {};

  auto stage = [&](int kt, int buf) {
#pragma unroll
    for (int c = 0; c < 4; ++c) {
      int gi = c * 256 + tid;
      int row = gi >> 3, gp = gi & 7;
      int gsrc = gp ^ (row & 7);
      int koff = kt * 64 + gsrc * 8;
      int ar = rowBase + row; ar = ar < M ? ar : M - 1;
      if (AF32) {
        const float* Af = (const float*)Ain + (size_t)ar * 256 + koff;
        float4 v0 = *(const float4*)Af;
        float4 v1 = *(const float4*)(Af + 4);
        f16x8 h = {(_Float16)v0.x, (_Float16)v0.y, (_Float16)v0.z, (_Float16)v0.w,
                   (_Float16)v1.x, (_Float16)v1.y, (_Float16)v1.z, (_Float16)v1.w};
        *(f16x8*)&lds[buf][0][gi * 8] = h;
      } else {
        gl16((const unsigned short*)Ain + (size_t)ar * 256 + koff, &lds[buf][0][gi * 8]);
      }
      int br = colBase + row;
      gl16(Bt + (size_t)br * 256 + koff, &lds[buf][1][gi * 8]);
    }
  };

  stage(0, 0);
  __syncthreads();

  for (int kt = 0; kt < 4; ++kt) {
    int buf = kt & 1;
    if (kt < 3) stage(kt + 1, buf ^ 1);  // prefetch next tile while computing this one

#pragma unroll
    for (int ks = 0; ks < 2; ++ks) {
      f16x8 a[4], b[4];
      int g = ks * 4 + l4;
#pragma unroll
      for (int mi = 0; mi < 4; ++mi) {
        int row = wr * 64 + mi * 16 + l15;
        int gp = g ^ (row & 7);
        a[mi] = *(const f16x8*)&lds[buf][0][row * 64 + gp * 8];
      }
#pragma unroll
      for (int ni = 0; ni < 4; ++ni) {
        int row = wc * 64 + ni * 16 + l15;
        int gp = g ^ (row & 7);
        b[ni] = *(const f16x8*)&lds[buf][1][row * 64 + gp * 8];
      }
#pragma unroll
      for (int mi = 0; mi < 4; ++mi)
#pragma unroll
        for (int ni = 0; ni < 4; ++ni)
          acc[mi][ni] = __builtin_amdgcn_mfma_f32_16x16x32_f16(a[mi], b[ni], acc[mi][ni], 0, 0, 0);
    }
    __syncthreads();  // drains prefetch vmem + protects buf reuse
  }

#pragma unroll
  for (int ni = 0; ni < 4; ++ni) {
    int col = colBase + wc * 64 + ni * 16 + l15;
    if (col < NSTORE) {
#pragma unroll
      for (int mi = 0; mi < 4; ++mi) {
        f32x4 v = acc[mi][ni];
#pragma unroll
        for (int i = 0; i < 4; ++i) {
          int r = rowBase + wr * 64 + mi * 16 + l4 * 4 + i;
          if (r < M) Cout[(size_t)r * NSTORE + col] = f16u(v[i]);
        }
      }
    }
  }
}

// ---------------- aggregation: one wave per node, fp16 T in / fp16 P out ----------------

__global__ __launch_bounds__(256) void agg256_kernel(
    const unsigned short* __restrict__ T, unsigned short* __restrict__ P,
    const int* __restrict__ rp, const int2* __restrict__ ew,
    const float* __restrict__ dis, const float* __restrict__ b) {
  int node = (blockIdx.x * blockDim.x + threadIdx.x) >> 6;
  int lane = threadIdx.x & 63;
  if (node >= NN) return;
  const ushort4* Tv = (const ushort4*)T;
  float4 bv = ((const float4*)b)[lane];
  float d = dis[node];
  float w0 = d * d;
  ushort4 t = Tv[(size_t)node * 64 + lane];
  float ax = bv.x + w0 * f16f(t.x), ay = bv.y + w0 * f16f(t.y);
  float az = bv.z + w0 * f16f(t.z), aw = bv.w + w0 * f16f(t.w);
  int e = rp[node], end = rp[node + 1];
  for (; e + 4 <= end; e += 4) {
    int2 e0 = ew[e], e1 = ew[e + 1], e2 = ew[e + 2], e3 = ew[e + 3];
    ushort4 t0 = Tv[(size_t)e0.x * 64 + lane];
    ushort4 t1 = Tv[(size_t)e1.x * 64 + lane];
    ushort4 t2 = Tv[(size_t)e2.x * 64 + lane];
    ushort4 t3 = Tv[(size_t)e3.x * 64 + lane];
    float f0 = __int_as_float(e0.y), f1 = __int_as_float(e1.y);
    float f2 = __int_as_float(e2.y), f3 = __int_as_float(e3.y);
    ax += f0 * f16f(t0.x) + f1 * f16f(t1.x) + f2 * f16f(t2.x) + f3 * f16f(t3.x);
    ay += f0 * f16f(t0.y) + f1 * f16f(t1.y) + f2 * f16f(t2.y) + f3 * f16f(t3.y);
    az += f0 * f16f(t0.z) + f1 * f16f(t1.z) + f2 * f16f(t2.z) + f3 * f16f(t3.z);
    aw += f0 * f16f(t0.w) + f1 * f16f(t1.w) + f2 * f16f(t2.w) + f3 * f16f(t3.w);
  }
  for (; e < end; ++e) {
    int2 sw = ew[e];
    float f = __int_as_float(sw.y);
    ushort4 ts = Tv[(size_t)sw.x * 64 + lane];
    ax += f * f16f(ts.x); ay += f * f16f(ts.y);
    az += f * f16f(ts.z); aw += f * f16f(ts.w);
  }
  ax = fmaxf(ax, 0.f); ay = fmaxf(ay, 0.f);
  az = fmaxf(az, 0.f); aw = fmaxf(aw, 0.f);
  ushort4 h;
  h.x = f16u(ax); h.y = f16u(ay); h.z = f16u(az); h.w = f16u(aw);
  ((ushort4*)P)[(size_t)node * 64 + lane] = h;
}

__global__ __launch_bounds__(256) void agg40_kernel(
    const unsigned short* __restrict__ T, float* __restrict__ O,
    const int* __restrict__ rp, const int2* __restrict__ ew,
    const float* __restrict__ dis, const float* __restrict__ b) {
  int node = (blockIdx.x * blockDim.x + threadIdx.x) >> 6;
  int lane = threadIdx.x & 63;
  if (node >= NN) return;
  float d = dis[node];
  int e = rp[node], end = rp[node + 1];
  if (lane < NC) {
    float acc = b[lane] + d * d * f16f(T[(size_t)node * NC + lane]);
    for (; e + 4 <= end; e += 4) {
      int2 e0 = ew[e], e1 = ew[e + 1], e2 = ew[e + 2], e3 = ew[e + 3];
      float t0 = f16f(T[(size_t)e0.x * NC + lane]);
      float t1 = f16f(T[(size_t)e1.x * NC + lane]);
      float t2 = f16f(T[(size_t)e2.x * NC + lane]);
      float t3 = f16f(T[(size_t)e3.x * NC + lane]);
      acc += __int_as_float(e0.y) * t0 + __int_as_float(e1.y) * t1 +
             __int_as_float(e2.y) * t2 + __int_as_float(e3.y) * t3;
    }
    for (; e < end; ++e) {
      int2 sw = ew[e];
      acc += __int_as_float(sw.y) * f16f(T[(size_t)sw.x * NC + lane]);
    }
    O[(size_t)node * NC + lane] = acc;
  }
}

// ---------------- launch ----------------

extern "C" void kernel_launch(void* const* d_in, const int* in_sizes, int n_in,
                              void* d_out, int out_size, void* d_ws, size_t ws_size,
                              hipStream_t stream) {
  const float* x  = (const float*)d_in[0];
  const int* edge = (const int*)d_in[1];
  const float* W1 = (const float*)d_in[2];
  const float* b1 = (const float*)d_in[3];
  const float* W2 = (const float*)d_in[4];
  const float* b2 = (const float*)d_in[5];
  const float* W3 = (const float*)d_in[6];
  const float* b3 = (const float*)d_in[7];
  const float* W4 = (const float*)d_in[8];
  const float* b4 = (const float*)d_in[9];
  float* out = (float*)d_out;

  char* p = (char*)d_ws;
  unsigned short* T16 = (unsigned short*)p; p += (size_t)NN * NH * 2;  // 25.6 MB
  unsigned short* P16 = (unsigned short*)p; p += (size_t)NN * NH * 2;  // 25.6 MB
  int* cnt = (int*)p;                p += (size_t)NN * 4;
  int* cur = (int*)p;                p += (size_t)NN * 4;   // adjacent to cnt: one memset
  float* dis = (float*)p;            p += (size_t)NN * 4;
  int* row_ptr = (int*)p;            p += (size_t)(NN + 16) * 4;
  int* bsum = (int*)p;               p += 256 * 4;
  int2* ew = (int2*)p;               p += (size_t)NE * 8;
  unsigned short* Wt1 = (unsigned short*)p; p += 256 * 256 * 2;
  unsigned short* Wt2 = (unsigned short*)p; p += 256 * 256 * 2;
  unsigned short* Wt3 = (unsigned short*)p; p += 256 * 256 * 2;
  unsigned short* Wt4 = (unsigned short*)p; p += 128 * 256 * 2;

  const int* e_src = edge;
  const int* e_dst = edge + NE;

  hipMemsetAsync(cnt, 0, (size_t)NN * 8, stream);  // cnt + cur

  const int nb1024 = (NN + 1023) / 1024;
  count_kernel<<<(NE + 255) / 256, 256, 0, stream>>>(e_dst, cnt);
  scan1_kernel<<<nb1024, 1024, 0, stream>>>(cnt, row_ptr, bsum, dis);
  scan23_kernel<<<nb1024, 1024, 0, stream>>>(row_ptr, bsum);
  scatter_kernel<<<(NE + 255) / 256, 256, 0, stream>>>(e_src, e_dst, row_ptr, cur, ew, dis);

  wf16_kernel<<<(229376 + 255) / 256, 256, 0, stream>>>(W1, W2, W3, W4, Wt1, Wt2, Wt3, Wt4);

  dim3 gFull((NN + 127) / 128, 2);
  dim3 gLast((NN + 127) / 128, 1);
  int aggBlocks = (NN * 64 + 255) / 256;

  gemm_f16<256, true><<<gFull, 256, 0, stream>>>(x, Wt1, T16, NN);   // A=f32 x, fused convert
  agg256_kernel<<<aggBlocks, 256, 0, stream>>>(T16, P16, row_ptr, ew, dis, b1);
  gemm_f16<256, false><<<gFull, 256, 0, stream>>>(P16, Wt2, T16, NN);
  agg256_kernel<<<aggBlocks, 256, 0, stream>>>(T16, P16, row_ptr, ew, dis, b2);
  gemm_f16<256, false><<<gFull, 256, 0, stream>>>(P16, Wt3, T16, NN);
  agg256_kernel<<<aggBlocks, 256, 0, stream>>>(T16, P16, row_ptr, ew, dis, b3);
  gemm_f16<NC, false><<<gLast, 256, 0, stream>>>(P16, Wt4, T16, NN);
  agg40_kernel<<<aggBlocks, 256, 0, stream>>>(T16, out, row_ptr, ew, dis, b4);
}